// Round 15
// baseline (438.432 us; speedup 1.0000x reference)
//
#include <hip/hip_runtime.h>
#include <hip/hip_bf16.h>

#define M_PTS 512
#define D_CLS 10
#define S_DIM 16384
#define K_DIM 1024
#define DIN_  784
#define PHI_ELEMS (5120 * 1024)

typedef short  bf16x8  __attribute__((ext_vector_type(8)));
typedef float  f32x4   __attribute__((ext_vector_type(4)));
typedef ushort ushort8 __attribute__((ext_vector_type(8)));

__device__ __forceinline__ ushort f2bfu(float f) {
    __bf16 h = (__bf16)f;                 // hardware RNE cvt on gfx950
    return __builtin_bit_cast(ushort, h);
}
__device__ __forceinline__ float bfu2f(ushort u) {
    uint x = (uint)u << 16;
    return __builtin_bit_cast(float, x);
}

// ---------------- mean = X @ W  (512x784 @ 784x10) ----------------
__global__ __launch_bounds__(64) void mean_kernel(const float* __restrict__ X,
                                                  const float* __restrict__ W,
                                                  float* __restrict__ out) {
    int m = blockIdx.x;
    int lane = threadIdx.x;
    float acc[D_CLS];
#pragma unroll
    for (int d = 0; d < D_CLS; ++d) acc[d] = 0.f;
    for (int i = lane; i < DIN_; i += 64) {
        float x = X[(size_t)m * DIN_ + i];
#pragma unroll
        for (int d = 0; d < D_CLS; ++d) acc[d] += x * W[i * D_CLS + d];
    }
#pragma unroll
    for (int d = 0; d < D_CLS; ++d) {
        float v = acc[d];
        for (int off = 32; off > 0; off >>= 1) v += __shfl_down(v, off);
        if (lane == 0) out[(size_t)m * D_CLS + d] = v;
    }
}

// ---------------- f32 -> bf16 streaming convert (n8 = elems/8) ---------------
__global__ __launch_bounds__(256) void cvt_a(const float* __restrict__ src,
                                             ushort* __restrict__ dst, int n8) {
    for (int i = blockIdx.x * 256 + threadIdx.x; i < n8; i += gridDim.x * 256) {
        float4 a = reinterpret_cast<const float4*>(src)[2 * i];
        float4 b = reinterpret_cast<const float4*>(src)[2 * i + 1];
        ushort8 o;
        o[0] = f2bfu(a.x); o[1] = f2bfu(a.y); o[2] = f2bfu(a.z); o[3] = f2bfu(a.w);
        o[4] = f2bfu(b.x); o[5] = f2bfu(b.y); o[6] = f2bfu(b.z); o[7] = f2bfu(b.w);
        reinterpret_cast<ushort8*>(dst)[i] = o;
    }
}

// ---------------- v (16384x1024 f32) -> vT (1024x16384 bf16) -----------------
__global__ __launch_bounds__(256) void cvt_bt(const float* __restrict__ v,
                                              ushort* __restrict__ bt) {
    __shared__ float tile[64][65];
    const int kt = blockIdx.x;   // 256 k-tiles
    const int ct = blockIdx.y;   // 16 col-tiles
    const int t  = threadIdx.x;
    const int col4 = t & 15, row = t >> 4;
#pragma unroll
    for (int i = 0; i < 4; ++i) {
        int r = row + 16 * i;
        float4 v4 = *reinterpret_cast<const float4*>(
            v + (size_t)(kt * 64 + r) * K_DIM + ct * 64 + col4 * 4);
        tile[r][col4 * 4 + 0] = v4.x; tile[r][col4 * 4 + 1] = v4.y;
        tile[r][col4 * 4 + 2] = v4.z; tile[r][col4 * 4 + 3] = v4.w;
    }
    __syncthreads();
#pragma unroll
    for (int i = 0; i < 2; ++i) {
        int cid = i * 256 + t;
        int c = cid >> 3, kc = cid & 7;
        ushort8 o;
#pragma unroll
        for (int j = 0; j < 8; ++j) o[j] = f2bfu(tile[kc * 8 + j][c]);
        *reinterpret_cast<ushort8*>(bt + (size_t)(ct * 64 + c) * S_DIM +
                                    kt * 64 + kc * 8) = o;
    }
}

// ---------------- gemm_cvp: fused-convert GEMM, r7 counted-vmcnt schedule ----
// C(5120x1024) = bf16(Jz_f32)(5120x16384) x BT(1024x16384)^T.
// 128x128 tile, BK=32, 256 thr = 4 waves (2M x 2N), wave tile 64x64.
// Staging/layout identical to r14's CORRECT kernel; only the sync skeleton
// changed: raw s_barrier + counted vmcnt (r7-proven) instead of __syncthreads
// (whose vmcnt(0) drain cost +500 cy/step in r14).
// Per iter s: {issue LOADA(s+2)[4 loads] + STAGE_B(s+2)[2 gload_lds];
//   COMPUTE(s); vmcnt(6) -> iter s-1's 6 loads landed (rX = A-tile s+1 regs,
//   B(s+1) staging) hidden under COMPUTE; WRITEA(abuf[(s+1)&1], rX);
//   lgkmcnt(0); s_barrier}.
// Race audit: WRITEA buf's readers passed iter s-1's barrier; STAGE_B
// overwrites bbuf[(s-1)%3] whose reads drained via lgkmcnt(0)+barrier.
template <int KSP>
__global__ __launch_bounds__(256, 3) void gemm_cvp(const float* __restrict__ A,
                                                   const ushort* __restrict__ BT,
                                                   ushort* __restrict__ Cout) {
    __shared__ ushort As[2][4096];   // 8 KB per buf (bf16)
    __shared__ ushort Bs[3][4096];   // 40 KB total

    const int nwg = 320 * KSP;
    const int lid = blockIdx.x;
    const int swz = (lid & 7) * (nwg >> 3) + (lid >> 3);   // bijective XCD swizzle
    const int kp  = swz / 320;
    const int rem = swz - kp * 320;
    const int bm  = rem >> 3;    // 0..39
    const int bn  = rem & 7;     // 0..7
    const int KSTEPS = 512 / KSP;                          // even
    const int kbase  = kp * (S_DIM / KSP);

    const int t  = threadIdx.x;
    const int l  = t & 63;
    const int wm = (t >> 7) & 1;
    const int wn = (t >> 6) & 1;
    const int lr = l & 15;
    const int kq = l >> 4;

    const float*  Ablk = A  + (size_t)(bm * 128) * S_DIM + kbase;
    const ushort* Bblk = BT + (size_t)(bn * 128) * S_DIM + kbase;

    // A staging: thread t owns chunks (r=t>>2, sl=t&3) and (r+64, sl);
    // LDS slot sl of row r holds global chunk sl^((r>>1)&3); csrc same for
    // both rows since f(r)=f(r+64). ds_write addr t*16 (+4096) = linear.
    const int   ar   = t >> 2;
    const int   csrc = (t & 3) ^ ((t >> 3) & 3);
    const float* ag0 = Ablk + (size_t)ar * S_DIM + csrc * 8;
    const float* ag1 = ag0 + (size_t)64 * S_DIM;

    float4 rA[4], rB[4];   // tile-parity register sets; all indices literal

    f32x4 acc[4][4];
#pragma unroll
    for (int i = 0; i < 4; ++i)
#pragma unroll
        for (int j = 0; j < 4; ++j) acc[i][j] = (f32x4)0.f;

#define LOADA(P, S)                                                             \
    { P[0] = *reinterpret_cast<const float4*>(ag0 + (size_t)(S) * 32);          \
      P[1] = *reinterpret_cast<const float4*>(ag0 + (size_t)(S) * 32 + 4);      \
      P[2] = *reinterpret_cast<const float4*>(ag1 + (size_t)(S) * 32);          \
      P[3] = *reinterpret_cast<const float4*>(ag1 + (size_t)(S) * 32 + 4); }

#define WRITEA(BUF, P)                                                          \
    { ushort8 o0, o1;                                                           \
      o0[0] = f2bfu(P[0].x); o0[1] = f2bfu(P[0].y);                             \
      o0[2] = f2bfu(P[0].z); o0[3] = f2bfu(P[0].w);                             \
      o0[4] = f2bfu(P[1].x); o0[5] = f2bfu(P[1].y);                             \
      o0[6] = f2bfu(P[1].z); o0[7] = f2bfu(P[1].w);                             \
      o1[0] = f2bfu(P[2].x); o1[1] = f2bfu(P[2].y);                             \
      o1[2] = f2bfu(P[2].z); o1[3] = f2bfu(P[2].w);                             \
      o1[4] = f2bfu(P[3].x); o1[5] = f2bfu(P[3].y);                             \
      o1[6] = f2bfu(P[3].z); o1[7] = f2bfu(P[3].w);                             \
      *reinterpret_cast<ushort8*>(&As[BUF][t * 8])        = o0;                 \
      *reinterpret_cast<ushort8*>(&As[BUF][t * 8 + 2048]) = o1; }

#define STAGE_B(BUF, S)                                                         \
    { _Pragma("unroll") for (int i = 0; i < 2; ++i) {                           \
        const int cch = i * 256 + t;                                            \
        const int r = cch >> 2, sl = cch & 3;                                   \
        const ushort* gp = Bblk + (size_t)r * S_DIM + (S) * 32 +                \
                           ((sl ^ ((r >> 1) & 3)) << 3);                        \
        ushort* lp = &Bs[BUF][(i * 256 + (t & 192)) * 8];                       \
        __builtin_amdgcn_global_load_lds(                                       \
            (const __attribute__((address_space(1))) void*)gp,                  \
            (__attribute__((address_space(3))) void*)lp, 16, 0, 0);             \
      } }

#define COMPUTE(AB, BB)                                                         \
    { bf16x8 fa[4], fb[4];                                                      \
      _Pragma("unroll") for (int mi = 0; mi < 4; ++mi) {                        \
        const int r = wm * 64 + mi * 16 + lr;                                   \
        fa[mi] = *reinterpret_cast<const bf16x8*>(                              \
            &As[AB][(r * 4 + (kq ^ ((r >> 1) & 3))) * 8]);                      \
      }                                                                         \
      _Pragma("unroll") for (int ni = 0; ni < 4; ++ni) {                        \
        const int c = wn * 64 + ni * 16 + lr;                                   \
        fb[ni] = *reinterpret_cast<const bf16x8*>(                              \
            &Bs[BB][(c * 4 + (kq ^ ((c >> 1) & 3))) * 8]);                      \
      }                                                                         \
      _Pragma("unroll") for (int ni = 0; ni < 4; ++ni)                          \
        _Pragma("unroll") for (int mi = 0; mi < 4; ++mi)                        \
          acc[mi][ni] = __builtin_amdgcn_mfma_f32_16x16x32_bf16(                \
              fa[mi], fb[ni], acc[mi][ni], 0, 0, 0);                            \
    }

    // prologue: B0[2] -> rA0[4] -> B1[2] -> rB1[4] issued; vmcnt(6) lands
    // the oldest 6 = {B0, rA}; write A-tile 0; barrier.
    STAGE_B(0, 0)
    LOADA(rA, 0)
    STAGE_B(1, 1)
    LOADA(rB, 1)
    asm volatile("s_waitcnt vmcnt(6)" ::: "memory");
    WRITEA(0, rA)
    asm volatile("s_waitcnt lgkmcnt(0)" ::: "memory");
    __builtin_amdgcn_s_barrier();
    __builtin_amdgcn_sched_barrier(0);

    const int NIT2 = KSTEPS / 2;
    for (int s2 = 0; s2 < NIT2; ++s2) {
        const int s = 2 * s2;
        // ---- even iter s: compute abuf0/bbuf[s%3]; rB holds tile s+1 ----
        if (s + 2 < KSTEPS) {
            LOADA(rA, s + 2)
            STAGE_B((s + 2) % 3, s + 2)
        }
        __builtin_amdgcn_s_setprio(1);
        COMPUTE(0, s % 3)
        __builtin_amdgcn_s_setprio(0);
        __builtin_amdgcn_sched_barrier(0);
        if (s + 2 < KSTEPS) { asm volatile("s_waitcnt vmcnt(6)" ::: "memory"); }
        else                { asm volatile("s_waitcnt vmcnt(0)" ::: "memory"); }
        WRITEA(1, rB)                                  // tile s+1 (landed)
        asm volatile("s_waitcnt lgkmcnt(0)" ::: "memory");
        __builtin_amdgcn_s_barrier();
        __builtin_amdgcn_sched_barrier(0);
        // ---- odd iter s+1: compute abuf1/bbuf[(s+1)%3]; rA holds tile s+2 --
        if (s + 3 < KSTEPS) {
            LOADA(rB, s + 3)
            STAGE_B((s + 3) % 3, s + 3)
        }
        __builtin_amdgcn_s_setprio(1);
        COMPUTE(1, (s + 1) % 3)
        __builtin_amdgcn_s_setprio(0);
        __builtin_amdgcn_sched_barrier(0);
        if (s + 3 < KSTEPS) { asm volatile("s_waitcnt vmcnt(6)" ::: "memory"); }
        else                { asm volatile("s_waitcnt vmcnt(0)" ::: "memory"); }
        if (s + 2 < KSTEPS) { WRITEA(0, rA) }          // tile s+2 (landed)
        asm volatile("s_waitcnt lgkmcnt(0)" ::: "memory");
        __builtin_amdgcn_s_barrier();
        __builtin_amdgcn_sched_barrier(0);
    }

    // epilogue: bf16 slab kp. C/D layout col=lane&15, row=(lane>>4)*4+reg.
    ushort* C = Cout + (size_t)kp * PHI_ELEMS;
#pragma unroll
    for (int mi = 0; mi < 4; ++mi) {
        int orow = bm * 128 + wm * 64 + mi * 16 + kq * 4;
#pragma unroll
        for (int ni = 0; ni < 4; ++ni) {
            int ocol = bn * 128 + wn * 64 + ni * 16 + lr;
            ushort* cp = C + (size_t)orow * K_DIM + ocol;
#pragma unroll
            for (int rr = 0; rr < 4; ++rr)
                cp[(size_t)rr * K_DIM] = f2bfu(acc[mi][ni][rr]);
        }
    }
#undef LOADA
#undef WRITEA
#undef STAGE_B
#undef COMPUTE
}

// ---------------- gemm_bb: r7-verified kernel, f32 C (T = phib x G) ----------
template <int SD, int KSP>
__global__ __launch_bounds__(256, 3) void gemm_bb(const ushort* __restrict__ A,
                                                  const ushort* __restrict__ BT,
                                                  float* __restrict__ Cout) {
    __shared__ ushort As[3][4096];
    __shared__ ushort Bs[3][4096];

    const int nwg = 320 * KSP;
    const int lid = blockIdx.x;
    const int swz = (lid & 7) * (nwg >> 3) + (lid >> 3);
    const int kp  = swz / 320;
    const int rem = swz - kp * 320;
    const int bm  = rem >> 3;
    const int bn  = rem & 7;
    const int KSTEPS = SD / 32 / KSP;
    const int kbase  = kp * (SD / KSP);

    const int t  = threadIdx.x;
    const int l  = t & 63;
    const int wm = (t >> 7) & 1;
    const int wn = (t >> 6) & 1;
    const int lr = l & 15;
    const int kq = l >> 4;

    const ushort* Ablk = A  + (size_t)(bm * 128) * SD + kbase;
    const ushort* Bblk = BT + (size_t)(bn * 128) * SD + kbase;

    f32x4 acc[4][4];
#pragma unroll
    for (int i = 0; i < 4; ++i)
#pragma unroll
        for (int j = 0; j < 4; ++j) acc[i][j] = (f32x4)0.f;

#define GSTAGE(BUF, S, SRC, DST)                                                \
    { _Pragma("unroll") for (int i = 0; i < 2; ++i) {                           \
        const int cch = i * 256 + t;                                            \
        const int r = cch >> 2, sl = cch & 3;                                   \
        const ushort* gp = SRC + (size_t)r * SD + (S) * 32 +                    \
                           ((sl ^ ((r >> 1) & 3)) << 3);                        \
        ushort* lp = &DST[BUF][(i * 256 + (t & 192)) * 8];                      \
        __builtin_amdgcn_global_load_lds(                                       \
            (const __attribute__((address_space(1))) void*)gp,                  \
            (__attribute__((address_space(3))) void*)lp, 16, 0, 0);             \
      } }

#define GCOMPUTE(BUF)                                                           \
    { bf16x8 fa[4], fb[4];                                                      \
      _Pragma("unroll") for (int mi = 0; mi < 4; ++mi) {                        \
        const int r = wm * 64 + mi * 16 + lr;                                   \
        fa[mi] = *reinterpret_cast<const bf16x8*>(                              \
            &As[BUF][(r * 4 + (kq ^ ((r >> 1) & 3))) * 8]);                     \
      }                                                                         \
      _Pragma("unroll") for (int ni = 0; ni < 4; ++ni) {                        \
        const int c = wn * 64 + ni * 16 + lr;                                   \
        fb[ni] = *reinterpret_cast<const bf16x8*>(                              \
            &Bs[BUF][(c * 4 + (kq ^ ((c >> 1) & 3))) * 8]);                     \
      }                                                                         \
      _Pragma("unroll") for (int ni = 0; ni < 4; ++ni)                          \
        _Pragma("unroll") for (int mi = 0; mi < 4; ++mi)                        \
          acc[mi][ni] = __builtin_amdgcn_mfma_f32_16x16x32_bf16(                \
              fa[mi], fb[ni], acc[mi][ni], 0, 0, 0);                            \
    }

    GSTAGE(0, 0, Ablk, As)
    GSTAGE(0, 0, Bblk, Bs)
    GSTAGE(1, 1, Ablk, As)
    GSTAGE(1, 1, Bblk, Bs)
    asm volatile("s_waitcnt vmcnt(4)" ::: "memory");
    __builtin_amdgcn_s_barrier();
    __builtin_amdgcn_sched_barrier(0);

    for (int s = 0; s < KSTEPS - 2; ++s) {
        const int sb = (s + 2) % 3, cb = s % 3;
        GSTAGE(sb, s + 2, Ablk, As)
        GSTAGE(sb, s + 2, Bblk, Bs)
        __builtin_amdgcn_s_setprio(1);
        GCOMPUTE(cb)
        __builtin_amdgcn_s_setprio(0);
        __builtin_amdgcn_sched_barrier(0);
        asm volatile("s_waitcnt vmcnt(4)" ::: "memory");
        __builtin_amdgcn_s_barrier();
        __builtin_amdgcn_sched_barrier(0);
    }
    {
        __builtin_amdgcn_s_setprio(1);
        GCOMPUTE((KSTEPS - 2) % 3)
        __builtin_amdgcn_s_setprio(0);
        __builtin_amdgcn_sched_barrier(0);
        asm volatile("s_waitcnt vmcnt(0)" ::: "memory");
        __builtin_amdgcn_s_barrier();
        __builtin_amdgcn_sched_barrier(0);
        GCOMPUTE((KSTEPS - 1) % 3)
    }

    float* C = Cout + (size_t)kp * PHI_ELEMS;
#pragma unroll
    for (int mi = 0; mi < 4; ++mi) {
        int orow = bm * 128 + wm * 64 + mi * 16 + kq * 4;
#pragma unroll
        for (int ni = 0; ni < 4; ++ni) {
            int ocol = bn * 128 + wn * 64 + ni * 16 + lr;
            float* cp = C + (size_t)orow * K_DIM + ocol;
#pragma unroll
            for (int rr = 0; rr < 4; ++rr) cp[(size_t)rr * K_DIM] = acc[mi][ni][rr];
        }
    }
#undef GSTAGE
#undef GCOMPUTE
}

// ---------------- sum KSP bf16 partial slabs -> phib (may alias slab 0) ------
template <int KSP>
__global__ __launch_bounds__(256) void phi_reduceN(const ushort* __restrict__ slabs,
                                                   ushort* __restrict__ phib) {
    const int n8 = PHI_ELEMS / 8;
    for (int i = blockIdx.x * 256 + threadIdx.x; i < n8; i += gridDim.x * 256) {
        float s[8] = {0.f, 0.f, 0.f, 0.f, 0.f, 0.f, 0.f, 0.f};
#pragma unroll
        for (int p = 0; p < KSP; ++p) {
            ushort8 u = reinterpret_cast<const ushort8*>(
                slabs + (size_t)p * PHI_ELEMS)[i];
#pragma unroll
            for (int j = 0; j < 8; ++j) s[j] += bfu2f(u[j]);
        }
        ushort8 o;
#pragma unroll
        for (int j = 0; j < 8; ++j) o[j] = f2bfu(s[j]);
        reinterpret_cast<ushort8*>(phib)[i] = o;   // elementwise: alias-safe
    }
}

// ---------------- var contract (bf16 P): var[n,a,b] = sum_g T[a,g] P[b,g] ---
__global__ __launch_bounds__(256) void var_contract_b(const float* __restrict__ T,
                                                      const ushort* __restrict__ P,
                                                      float* __restrict__ out) {
    __shared__ float red[4][56];
    const int n = blockIdx.x, t = threadIdx.x, lane = t & 63, wid = t >> 6;
    const float*  Tn = T + (size_t)n * D_CLS * K_DIM;
    const ushort* Pn = P + (size_t)n * D_CLS * K_DIM;
    float Ta[D_CLS][4], Pb[D_CLS][4];
#pragma unroll
    for (int a = 0; a < D_CLS; ++a)
#pragma unroll
        for (int j = 0; j < 4; ++j) {
            Ta[a][j] = Tn[a * K_DIM + t + 256 * j];
            Pb[a][j] = bfu2f(Pn[a * K_DIM + t + 256 * j]);
        }
    int p = 0;
#pragma unroll
    for (int a = 0; a < D_CLS; ++a)
#pragma unroll
        for (int b = 0; b <= a; ++b, ++p) {
            float s = Ta[a][0] * Pb[b][0] + Ta[a][1] * Pb[b][1]
                    + Ta[a][2] * Pb[b][2] + Ta[a][3] * Pb[b][3];
#pragma unroll
            for (int off = 32; off > 0; off >>= 1) s += __shfl_down(s, off);
            if (lane == 0) red[wid][p] = s;
        }
    __syncthreads();
    if (t < 55) {
        int a = 0;
        while ((a + 1) * (a + 2) / 2 <= t) ++a;
        int b = t - a * (a + 1) / 2;
        float s = red[0][t] + red[1][t] + red[2][t] + red[3][t];
        float* vout = out + M_PTS * D_CLS + (size_t)n * D_CLS * D_CLS;
        vout[a * D_CLS + b] = s;
        vout[b * D_CLS + a] = s;
    }
}

extern "C" void kernel_launch(void* const* d_in, const int* in_sizes, int n_in,
                              void* d_out, int out_size, void* d_ws, size_t ws_size,
                              hipStream_t stream) {
    const float* X  = (const float*)d_in[0];
    const float* Jz = (const float*)d_in[1];
    const float* v  = (const float*)d_in[2];
    const float* G  = (const float*)d_in[3];
    const float* W  = (const float*)d_in[4];
    float* out = (float*)d_out;
    float* ws  = (float*)d_ws;

    const size_t PHB  = (size_t)PHI_ELEMS * 2;               // 10.5 MB bf16 slab
    const size_t BT_B = (size_t)K_DIM * S_DIM * 2;           // vTbf  33.6 MB
    const size_t G_B  = (size_t)K_DIM * K_DIM * 2;           // Gbf    2.1 MB
    // KSP=4: slabs(42) + vT + G; T overlays slabs 2-3 (dead after reduce).
    const size_t NEED4 = 4 * PHB + BT_B + G_B;               // ~77.7 MB
    const size_t NEED1 = PHB + BT_B + G_B + (size_t)PHI_ELEMS * 4;  // ~67 MB
    (void)NEED1;

    hipLaunchKernelGGL(mean_kernel, dim3(M_PTS), dim3(64), 0, stream, X, W, out);

    const int KSP = (ws_size >= NEED4) ? 4 : 1;
    ushort* slabs = (ushort*)ws;
    ushort* vTb   = slabs + (size_t)KSP * PHI_ELEMS;
    ushort* Gb    = vTb + (size_t)K_DIM * S_DIM;
    ushort* phib  = slabs;                                   // alias slab 0
    float*  T     = (KSP == 4) ? (float*)(slabs + (size_t)2 * PHI_ELEMS)
                               : (float*)(Gb + (size_t)K_DIM * K_DIM);

    hipLaunchKernelGGL(cvt_bt, dim3(256, 16), dim3(256), 0, stream, v, vTb);
    hipLaunchKernelGGL(cvt_a, dim3(256), dim3(256), 0, stream,
                       G, Gb, K_DIM * K_DIM / 8);
    if (KSP == 4) {
        hipLaunchKernelGGL(gemm_cvp<4>, dim3(1280), dim3(256), 0, stream,
                           Jz, vTb, slabs);
        hipLaunchKernelGGL(phi_reduceN<4>, dim3(1024), dim3(256), 0, stream,
                           slabs, phib);
    } else {
        hipLaunchKernelGGL(gemm_cvp<1>, dim3(320), dim3(256), 0, stream,
                           Jz, vTb, slabs);                  // slab0 == phib
    }
    hipLaunchKernelGGL((gemm_bb<K_DIM, 1>), dim3(320), dim3(256), 0, stream,
                       phib, Gb, T);
    hipLaunchKernelGGL(var_contract_b, dim3(M_PTS), dim3(256), 0, stream,
                       T, phib, out);
}

// Round 16
// 409.339 us; speedup vs baseline: 1.0711x; 1.0711x over previous
//
#include <hip/hip_runtime.h>
#include <hip/hip_bf16.h>

#define M_PTS 512
#define D_CLS 10
#define S_DIM 16384
#define K_DIM 1024
#define DIN_  784
#define PHI_ELEMS (5120 * 1024)

typedef short  bf16x8  __attribute__((ext_vector_type(8)));
typedef float  f32x4   __attribute__((ext_vector_type(4)));
typedef ushort ushort8 __attribute__((ext_vector_type(8)));

__device__ __forceinline__ ushort f2bfu(float f) {
    __bf16 h = (__bf16)f;                 // hardware RNE cvt on gfx950
    return __builtin_bit_cast(ushort, h);
}
__device__ __forceinline__ float bfu2f(ushort u) {
    uint x = (uint)u << 16;
    return __builtin_bit_cast(float, x);
}

// ---------------- mean = X @ W  (512x784 @ 784x10) ----------------
__global__ __launch_bounds__(64) void mean_kernel(const float* __restrict__ X,
                                                  const float* __restrict__ W,
                                                  float* __restrict__ out) {
    int m = blockIdx.x;
    int lane = threadIdx.x;
    float acc[D_CLS];
#pragma unroll
    for (int d = 0; d < D_CLS; ++d) acc[d] = 0.f;
    for (int i = lane; i < DIN_; i += 64) {
        float x = X[(size_t)m * DIN_ + i];
#pragma unroll
        for (int d = 0; d < D_CLS; ++d) acc[d] += x * W[i * D_CLS + d];
    }
#pragma unroll
    for (int d = 0; d < D_CLS; ++d) {
        float v = acc[d];
        for (int off = 32; off > 0; off >>= 1) v += __shfl_down(v, off);
        if (lane == 0) out[(size_t)m * D_CLS + d] = v;
    }
}

// ---------------- f32 -> bf16 streaming convert (n8 = elems/8) ---------------
__global__ __launch_bounds__(256) void cvt_a(const float* __restrict__ src,
                                             ushort* __restrict__ dst, int n8) {
    for (int i = blockIdx.x * 256 + threadIdx.x; i < n8; i += gridDim.x * 256) {
        float4 a = reinterpret_cast<const float4*>(src)[2 * i];
        float4 b = reinterpret_cast<const float4*>(src)[2 * i + 1];
        ushort8 o;
        o[0] = f2bfu(a.x); o[1] = f2bfu(a.y); o[2] = f2bfu(a.z); o[3] = f2bfu(a.w);
        o[4] = f2bfu(b.x); o[5] = f2bfu(b.y); o[6] = f2bfu(b.z); o[7] = f2bfu(b.w);
        reinterpret_cast<ushort8*>(dst)[i] = o;
    }
}

// ---------------- v (16384x1024 f32) -> vT (1024x16384 bf16) -----------------
__global__ __launch_bounds__(256) void cvt_bt(const float* __restrict__ v,
                                              ushort* __restrict__ bt) {
    __shared__ float tile[64][65];
    const int kt = blockIdx.x;   // 256 k-tiles
    const int ct = blockIdx.y;   // 16 col-tiles
    const int t  = threadIdx.x;
    const int col4 = t & 15, row = t >> 4;
#pragma unroll
    for (int i = 0; i < 4; ++i) {
        int r = row + 16 * i;
        float4 v4 = *reinterpret_cast<const float4*>(
            v + (size_t)(kt * 64 + r) * K_DIM + ct * 64 + col4 * 4);
        tile[r][col4 * 4 + 0] = v4.x; tile[r][col4 * 4 + 1] = v4.y;
        tile[r][col4 * 4 + 2] = v4.z; tile[r][col4 * 4 + 3] = v4.w;
    }
    __syncthreads();
#pragma unroll
    for (int i = 0; i < 2; ++i) {
        int cid = i * 256 + t;
        int c = cid >> 3, kc = cid & 7;
        ushort8 o;
#pragma unroll
        for (int j = 0; j < 8; ++j) o[j] = f2bfu(tile[kc * 8 + j][c]);
        *reinterpret_cast<ushort8*>(bt + (size_t)(ct * 64 + c) * S_DIM +
                                    kt * 64 + kc * 8) = o;
    }
}

// ---------------- gemm_bs: r7-verified 128x128 depth-3 kernel, bf16 C out ----
// C(5120 x 1024) = A(5120 x SD) x BT(1024 x SD)^T, bf16 row-major [*][SD].
// BK=32, 256 threads = 4 waves (2M x 2N), wave tile 64x64.
// LDS swizzle f(r)=(r>>1)&3 (conflict-free, verified r6/r7: SQ_LDS_BANK_
// CONFLICT = 0). Depth-3 pipeline, counted vmcnt(4): tile s+2 stays in
// flight across barriers; never drains to 0 mid-loop. Measured 251 us (r12).
// Epilogue writes bf16 partial slab kp (r8-r12-verified chain).
template <int SD, int KSP>
__global__ __launch_bounds__(256, 3) void gemm_bs(const ushort* __restrict__ A,
                                                  const ushort* __restrict__ BT,
                                                  ushort* __restrict__ Cout) {
    __shared__ ushort As[3][4096];   // 8 KB per buf
    __shared__ ushort Bs[3][4096];   // 48 KB total -> 3 blocks/CU

    const int nwg = 320 * KSP;
    const int lid = blockIdx.x;
    const int swz = (lid & 7) * (nwg >> 3) + (lid >> 3);   // bijective XCD swizzle
    const int kp  = swz / 320;
    const int rem = swz - kp * 320;
    const int bm  = rem >> 3;    // 0..39
    const int bn  = rem & 7;     // 0..7
    const int KSTEPS = SD / 32 / KSP;
    const int kbase  = kp * (SD / KSP);

    const int t  = threadIdx.x;
    const int l  = t & 63;
    const int wm = (t >> 7) & 1;
    const int wn = (t >> 6) & 1;
    const int lr = l & 15;
    const int kq = l >> 4;

    const ushort* Ablk = A  + (size_t)(bm * 128) * SD + kbase;
    const ushort* Bblk = BT + (size_t)(bn * 128) * SD + kbase;

    f32x4 acc[4][4];
#pragma unroll
    for (int i = 0; i < 4; ++i)
#pragma unroll
        for (int j = 0; j < 4; ++j) acc[i][j] = (f32x4)0.f;

#define GSTAGE(BUF, S, SRC, DST)                                                \
    { _Pragma("unroll") for (int i = 0; i < 2; ++i) {                           \
        const int cch = i * 256 + t;                                            \
        const int r = cch >> 2, sl = cch & 3;                                   \
        const ushort* gp = SRC + (size_t)r * SD + (S) * 32 +                    \
                           ((sl ^ ((r >> 1) & 3)) << 3);                        \
        ushort* lp = &DST[BUF][(i * 256 + (t & 192)) * 8];                      \
        __builtin_amdgcn_global_load_lds(                                       \
            (const __attribute__((address_space(1))) void*)gp,                  \
            (__attribute__((address_space(3))) void*)lp, 16, 0, 0);             \
      } }

#define GCOMPUTE(BUF)                                                           \
    { bf16x8 fa[4], fb[4];                                                      \
      _Pragma("unroll") for (int mi = 0; mi < 4; ++mi) {                        \
        const int r = wm * 64 + mi * 16 + lr;                                   \
        fa[mi] = *reinterpret_cast<const bf16x8*>(                              \
            &As[BUF][(r * 4 + (kq ^ ((r >> 1) & 3))) * 8]);                     \
      }                                                                         \
      _Pragma("unroll") for (int ni = 0; ni < 4; ++ni) {                        \
        const int c = wn * 64 + ni * 16 + lr;                                   \
        fb[ni] = *reinterpret_cast<const bf16x8*>(                              \
            &Bs[BUF][(c * 4 + (kq ^ ((c >> 1) & 3))) * 8]);                     \
      }                                                                         \
      _Pragma("unroll") for (int ni = 0; ni < 4; ++ni)                          \
        _Pragma("unroll") for (int mi = 0; mi < 4; ++mi)                        \
          acc[mi][ni] = __builtin_amdgcn_mfma_f32_16x16x32_bf16(                \
              fa[mi], fb[ni], acc[mi][ni], 0, 0, 0);                            \
    }

    GSTAGE(0, 0, Ablk, As)
    GSTAGE(0, 0, Bblk, Bs)
    GSTAGE(1, 1, Ablk, As)
    GSTAGE(1, 1, Bblk, Bs)
    asm volatile("s_waitcnt vmcnt(4)" ::: "memory");
    __builtin_amdgcn_s_barrier();
    __builtin_amdgcn_sched_barrier(0);

    for (int s = 0; s < KSTEPS - 2; ++s) {
        const int sb = (s + 2) % 3, cb = s % 3;
        GSTAGE(sb, s + 2, Ablk, As)
        GSTAGE(sb, s + 2, Bblk, Bs)
        __builtin_amdgcn_s_setprio(1);
        GCOMPUTE(cb)
        __builtin_amdgcn_s_setprio(0);
        __builtin_amdgcn_sched_barrier(0);
        asm volatile("s_waitcnt vmcnt(4)" ::: "memory");
        __builtin_amdgcn_s_barrier();
        __builtin_amdgcn_sched_barrier(0);
    }
    {
        __builtin_amdgcn_s_setprio(1);
        GCOMPUTE((KSTEPS - 2) % 3)
        __builtin_amdgcn_s_setprio(0);
        __builtin_amdgcn_sched_barrier(0);
        asm volatile("s_waitcnt vmcnt(0)" ::: "memory");
        __builtin_amdgcn_s_barrier();
        __builtin_amdgcn_sched_barrier(0);
        GCOMPUTE((KSTEPS - 1) % 3)
    }

    // epilogue: bf16 slab kp. C/D layout col=lane&15, row=(lane>>4)*4+reg.
    ushort* C = Cout + (size_t)kp * PHI_ELEMS;
#pragma unroll
    for (int mi = 0; mi < 4; ++mi) {
        int orow = bm * 128 + wm * 64 + mi * 16 + kq * 4;
#pragma unroll
        for (int ni = 0; ni < 4; ++ni) {
            int ocol = bn * 128 + wn * 64 + ni * 16 + lr;
            ushort* cp = C + (size_t)orow * K_DIM + ocol;
#pragma unroll
            for (int rr = 0; rr < 4; ++rr)
                cp[(size_t)rr * K_DIM] = f2bfu(acc[mi][ni][rr]);
        }
    }
#undef GSTAGE
#undef GCOMPUTE
}

// ---------------- gemm_bb: identical structure, f32 C (T = phib x G) ---------
template <int SD, int KSP>
__global__ __launch_bounds__(256, 3) void gemm_bb(const ushort* __restrict__ A,
                                                  const ushort* __restrict__ BT,
                                                  float* __restrict__ Cout) {
    __shared__ ushort As[3][4096];
    __shared__ ushort Bs[3][4096];

    const int nwg = 320 * KSP;
    const int lid = blockIdx.x;
    const int swz = (lid & 7) * (nwg >> 3) + (lid >> 3);
    const int kp  = swz / 320;
    const int rem = swz - kp * 320;
    const int bm  = rem >> 3;
    const int bn  = rem & 7;
    const int KSTEPS = SD / 32 / KSP;
    const int kbase  = kp * (SD / KSP);

    const int t  = threadIdx.x;
    const int l  = t & 63;
    const int wm = (t >> 7) & 1;
    const int wn = (t >> 6) & 1;
    const int lr = l & 15;
    const int kq = l >> 4;

    const ushort* Ablk = A  + (size_t)(bm * 128) * SD + kbase;
    const ushort* Bblk = BT + (size_t)(bn * 128) * SD + kbase;

    f32x4 acc[4][4];
#pragma unroll
    for (int i = 0; i < 4; ++i)
#pragma unroll
        for (int j = 0; j < 4; ++j) acc[i][j] = (f32x4)0.f;

#define GSTAGE(BUF, S, SRC, DST)                                                \
    { _Pragma("unroll") for (int i = 0; i < 2; ++i) {                           \
        const int cch = i * 256 + t;                                            \
        const int r = cch >> 2, sl = cch & 3;                                   \
        const ushort* gp = SRC + (size_t)r * SD + (S) * 32 +                    \
                           ((sl ^ ((r >> 1) & 3)) << 3);                        \
        ushort* lp = &DST[BUF][(i * 256 + (t & 192)) * 8];                      \
        __builtin_amdgcn_global_load_lds(                                       \
            (const __attribute__((address_space(1))) void*)gp,                  \
            (__attribute__((address_space(3))) void*)lp, 16, 0, 0);             \
      } }

#define GCOMPUTE(BUF)                                                           \
    { bf16x8 fa[4], fb[4];                                                      \
      _Pragma("unroll") for (int mi = 0; mi < 4; ++mi) {                        \
        const int r = wm * 64 + mi * 16 + lr;                                   \
        fa[mi] = *reinterpret_cast<const bf16x8*>(                              \
            &As[BUF][(r * 4 + (kq ^ ((r >> 1) & 3))) * 8]);                     \
      }                                                                         \
      _Pragma("unroll") for (int ni = 0; ni < 4; ++ni) {                        \
        const int c = wn * 64 + ni * 16 + lr;                                   \
        fb[ni] = *reinterpret_cast<const bf16x8*>(                              \
            &Bs[BUF][(c * 4 + (kq ^ ((c >> 1) & 3))) * 8]);                     \
      }                                                                         \
      _Pragma("unroll") for (int ni = 0; ni < 4; ++ni)                          \
        _Pragma("unroll") for (int mi = 0; mi < 4; ++mi)                        \
          acc[mi][ni] = __builtin_amdgcn_mfma_f32_16x16x32_bf16(                \
              fa[mi], fb[ni], acc[mi][ni], 0, 0, 0);                            \
    }

    GSTAGE(0, 0, Ablk, As)
    GSTAGE(0, 0, Bblk, Bs)
    GSTAGE(1, 1, Ablk, As)
    GSTAGE(1, 1, Bblk, Bs)
    asm volatile("s_waitcnt vmcnt(4)" ::: "memory");
    __builtin_amdgcn_s_barrier();
    __builtin_amdgcn_sched_barrier(0);

    for (int s = 0; s < KSTEPS - 2; ++s) {
        const int sb = (s + 2) % 3, cb = s % 3;
        GSTAGE(sb, s + 2, Ablk, As)
        GSTAGE(sb, s + 2, Bblk, Bs)
        __builtin_amdgcn_s_setprio(1);
        GCOMPUTE(cb)
        __builtin_amdgcn_s_setprio(0);
        __builtin_amdgcn_sched_barrier(0);
        asm volatile("s_waitcnt vmcnt(4)" ::: "memory");
        __builtin_amdgcn_s_barrier();
        __builtin_amdgcn_sched_barrier(0);
    }
    {
        __builtin_amdgcn_s_setprio(1);
        GCOMPUTE((KSTEPS - 2) % 3)
        __builtin_amdgcn_s_setprio(0);
        __builtin_amdgcn_sched_barrier(0);
        asm volatile("s_waitcnt vmcnt(0)" ::: "memory");
        __builtin_amdgcn_s_barrier();
        __builtin_amdgcn_sched_barrier(0);
        GCOMPUTE((KSTEPS - 1) % 3)
    }

    float* C = Cout + (size_t)kp * PHI_ELEMS;
#pragma unroll
    for (int mi = 0; mi < 4; ++mi) {
        int orow = bm * 128 + wm * 64 + mi * 16 + kq * 4;
#pragma unroll
        for (int ni = 0; ni < 4; ++ni) {
            int ocol = bn * 128 + wn * 64 + ni * 16 + lr;
            float* cp = C + (size_t)orow * K_DIM + ocol;
#pragma unroll
            for (int rr = 0; rr < 4; ++rr) cp[(size_t)rr * K_DIM] = acc[mi][ni][rr];
        }
    }
#undef GSTAGE
#undef GCOMPUTE
}

// ---------------- sum KSP bf16 partial slabs -> phib (may alias slab 0) ------
template <int KSP>
__global__ __launch_bounds__(256) void phi_reduceN(const ushort* __restrict__ slabs,
                                                   ushort* __restrict__ phib) {
    const int n8 = PHI_ELEMS / 8;
    for (int i = blockIdx.x * 256 + threadIdx.x; i < n8; i += gridDim.x * 256) {
        float s[8] = {0.f, 0.f, 0.f, 0.f, 0.f, 0.f, 0.f, 0.f};
#pragma unroll
        for (int p = 0; p < KSP; ++p) {
            ushort8 u = reinterpret_cast<const ushort8*>(
                slabs + (size_t)p * PHI_ELEMS)[i];
#pragma unroll
            for (int j = 0; j < 8; ++j) s[j] += bfu2f(u[j]);
        }
        ushort8 o;
#pragma unroll
        for (int j = 0; j < 8; ++j) o[j] = f2bfu(s[j]);
        reinterpret_cast<ushort8*>(phib)[i] = o;   // elementwise: alias-safe
    }
}

// ---------------- var contract (bf16 P): var[n,a,b] = sum_g T[a,g] P[b,g] ---
__global__ __launch_bounds__(256) void var_contract_b(const float* __restrict__ T,
                                                      const ushort* __restrict__ P,
                                                      float* __restrict__ out) {
    __shared__ float red[4][56];
    const int n = blockIdx.x, t = threadIdx.x, lane = t & 63, wid = t >> 6;
    const float*  Tn = T + (size_t)n * D_CLS * K_DIM;
    const ushort* Pn = P + (size_t)n * D_CLS * K_DIM;
    float Ta[D_CLS][4], Pb[D_CLS][4];
#pragma unroll
    for (int a = 0; a < D_CLS; ++a)
#pragma unroll
        for (int j = 0; j < 4; ++j) {
            Ta[a][j] = Tn[a * K_DIM + t + 256 * j];
            Pb[a][j] = bfu2f(Pn[a * K_DIM + t + 256 * j]);
        }
    int p = 0;
#pragma unroll
    for (int a = 0; a < D_CLS; ++a)
#pragma unroll
        for (int b = 0; b <= a; ++b, ++p) {
            float s = Ta[a][0] * Pb[b][0] + Ta[a][1] * Pb[b][1]
                    + Ta[a][2] * Pb[b][2] + Ta[a][3] * Pb[b][3];
#pragma unroll
            for (int off = 32; off > 0; off >>= 1) s += __shfl_down(s, off);
            if (lane == 0) red[wid][p] = s;
        }
    __syncthreads();
    if (t < 55) {
        int a = 0;
        while ((a + 1) * (a + 2) / 2 <= t) ++a;
        int b = t - a * (a + 1) / 2;
        float s = red[0][t] + red[1][t] + red[2][t] + red[3][t];
        float* vout = out + M_PTS * D_CLS + (size_t)n * D_CLS * D_CLS;
        vout[a * D_CLS + b] = s;
        vout[b * D_CLS + a] = s;
    }
}

extern "C" void kernel_launch(void* const* d_in, const int* in_sizes, int n_in,
                              void* d_out, int out_size, void* d_ws, size_t ws_size,
                              hipStream_t stream) {
    const float* X  = (const float*)d_in[0];
    const float* Jz = (const float*)d_in[1];
    const float* v  = (const float*)d_in[2];
    const float* G  = (const float*)d_in[3];
    const float* W  = (const float*)d_in[4];
    float* out = (float*)d_out;
    float* ws  = (float*)d_ws;

    const size_t PHB  = (size_t)PHI_ELEMS * 2;               // 10.5 MB bf16 slab
    const size_t A_B  = (size_t)5120 * S_DIM * 2;            // Abf  167.8 MB
    const size_t BT_B = (size_t)K_DIM * S_DIM * 2;           // vTbf  33.6 MB
    const size_t G_B  = (size_t)K_DIM * K_DIM * 2;           // Gbf    2.1 MB
    // overlays: phib aliases slab0 (elementwise reduce, r11-verified); T
    // aliases slabs 2-3 (KSP=4, dead after reduce) or dead Abf (KSP=1).
    const size_t NEED4 = 4 * PHB + BT_B + G_B + A_B;         // ~245.5 MB
    const size_t NEED1 = 1 * PHB + BT_B + G_B + A_B;         // ~214 MB
    (void)NEED1;

    hipLaunchKernelGGL(mean_kernel, dim3(M_PTS), dim3(64), 0, stream, X, W, out);

    const int KSP = (ws_size >= NEED4) ? 4 : 1;
    ushort* slabs = (ushort*)ws;
    ushort* vTb   = slabs + (size_t)KSP * PHI_ELEMS;
    ushort* Gb    = vTb + (size_t)K_DIM * S_DIM;
    ushort* Abf   = Gb + (size_t)K_DIM * K_DIM;
    ushort* phib  = slabs;                                   // alias slab 0
    float*  T     = (KSP == 4) ? (float*)(slabs + (size_t)2 * PHI_ELEMS)
                               : (float*)Abf;                // dead regions

    hipLaunchKernelGGL(cvt_a, dim3(2048), dim3(256), 0, stream,
                       Jz, Abf, 5120 * S_DIM / 8);
    hipLaunchKernelGGL(cvt_bt, dim3(256, 16), dim3(256), 0, stream, v, vTb);
    hipLaunchKernelGGL(cvt_a, dim3(256), dim3(256), 0, stream,
                       G, Gb, K_DIM * K_DIM / 8);
    if (KSP == 4) {
        hipLaunchKernelGGL((gemm_bs<S_DIM, 4>), dim3(1280), dim3(256), 0,
                           stream, Abf, vTb, slabs);
        hipLaunchKernelGGL(phi_reduceN<4>, dim3(1024), dim3(256), 0, stream,
                           slabs, phib);
    } else {
        hipLaunchKernelGGL((gemm_bs<S_DIM, 1>), dim3(320), dim3(256), 0,
                           stream, Abf, vTb, slabs);         // slab0 == phib
    }
    hipLaunchKernelGGL((gemm_bb<K_DIM, 1>), dim3(320), dim3(256), 0, stream,
                       phib, Gb, T);
    hipLaunchKernelGGL(var_contract_b, dim3(M_PTS), dim3(256), 0, stream,
                       T, phib, out);
}